// Round 9
// baseline (409.269 us; speedup 1.0000x reference)
//
#include <hip/hip_runtime.h>

#define DD 128   // feature dim
#define NP 256   // node partitions
#define EB 4096  // edges per binning block

typedef float4 f4;
typedef __attribute__((ext_vector_type(8))) short bf16x8;
typedef __attribute__((ext_vector_type(4))) float f32x4;

__device__ __forceinline__ short toBf(float f) {
    unsigned u = __float_as_uint(f);
    u += 0x7fff + ((u >> 16) & 1);   // RNE
    return (short)(u >> 16);
}

// ---------------- setup: LDS-binned counting sort (no global atomics) ----------------
// payload packing (32-bit): [31:21] local bucket (dloc*T+k, <2048) | [18:17] k | [16:0] s

__global__ __launch_bounds__(1024) void kAF(const int* __restrict__ ei, int E, int PSZ, int nbA,
                                            int* __restrict__ cntB_D, int* __restrict__ cntB_S,
                                            const float* __restrict__ W, ushort* __restrict__ WT,
                                            int totW, int nPW,
                                            const float* __restrict__ x, ushort* __restrict__ xb,
                                            int n8) {
    __shared__ int hd[NP], hs[NP];
    int tid = threadIdx.x, b = blockIdx.x;
    if (b < nbA) {
        if (tid < NP) { hd[tid] = 0; hs[tid] = 0; }
        __syncthreads();
        int base = b * EB;
        int lim = min(base + EB, E);
        for (int e = base + tid; e < lim; e += 1024) {
            int s = ei[e], d = ei[E + e];
            atomicAdd(&hs[s / PSZ], 1);
            atomicAdd(&hd[d / PSZ], 1);
        }
        __syncthreads();
        if (tid < NP) {
            cntB_D[tid * nbA + b] = hd[tid];
            cntB_S[tid * nbA + b] = hs[tid];
        }
    } else if (b < nbA + nPW) {
        int i = (b - nbA) * 1024 + tid;
        if (i < totW) {
            int k = i >> 14, rem = i & 16383, j = rem >> 7, d = rem & 127;
            WT[i] = (ushort)toBf(W[(size_t)k * 16384 + (size_t)d * DD + j]);  // WT[k][j][d] = W[k][d][j]
        }
    } else {
        int i = (b - nbA - nPW) * 1024 + tid;
        if (i < n8) {
            const f4* q = (const f4*)(x + (size_t)i * 8);
            f4 lo = q[0], hi = q[1];
            bf16x8 r;
            r[0] = toBf(lo.x); r[1] = toBf(lo.y); r[2] = toBf(lo.z); r[3] = toBf(lo.w);
            r[4] = toBf(hi.x); r[5] = toBf(hi.y); r[6] = toBf(hi.z); r[7] = toBf(hi.w);
            *(bf16x8*)(xb + (size_t)i * 8) = r;
        }
    }
}

__global__ __launch_bounds__(512) void kB1(int* __restrict__ cntB_D, int* __restrict__ cntB_S,
                                           int nbA,
                                           int* __restrict__ partTotD, int* __restrict__ partTotS) {
    __shared__ int sh[512];
    int b = blockIdx.x, tid = threadIdx.x;
    int* cntB = (b < NP) ? cntB_D : cntB_S;
    int* partTot = (b < NP) ? partTotD : partTotS;
    int p = (b < NP) ? b : b - NP;
    int v = (tid < nbA) ? cntB[p * nbA + tid] : 0;
    sh[tid] = v; __syncthreads();
    for (int off = 1; off < 512; off <<= 1) {
        int add = (tid >= off) ? sh[tid - off] : 0;
        __syncthreads(); sh[tid] += add; __syncthreads();
    }
    if (tid < nbA) cntB[p * nbA + tid] = sh[tid] - v;   // local exclusive prefix
    if (tid == 511) partTot[p] = sh[511];
}

__global__ __launch_bounds__(1024) void kC(const int* __restrict__ ei, const int* __restrict__ ea,
                                           int E, int N, int T, int PSZ, int nbA,
                                           const int* __restrict__ cntB_D, const int* __restrict__ cntB_S,
                                           const int* __restrict__ partTotD,
                                           const int* __restrict__ partTotS,
                                           int* __restrict__ binD, ushort* __restrict__ binS) {
    __shared__ int pd[NP], ps[NP];
    __shared__ int sc[512];
    int tid = threadIdx.x, b = blockIdx.x;
    if (tid < 512) sc[tid] = (tid < 256) ? partTotD[tid] : partTotS[tid - 256];
    __syncthreads();
    for (int off = 1; off < 256; off <<= 1) {
        int add = 0;
        if (tid < 512 && (tid & 255) >= off) add = sc[tid - off];
        __syncthreads();
        if (tid < 512) sc[tid] += add;
        __syncthreads();
    }
    if (tid < NP) {
        pd[tid] = cntB_D[tid * nbA + b] + (sc[tid] - partTotD[tid]);
        ps[tid] = cntB_S[tid * nbA + b] + (sc[tid + 256] - partTotS[tid]);
    }
    __syncthreads();
    int base = b * EB;
    int lim = min(base + EB, E);
    for (int e = base + tid; e < lim; e += 1024) {
        int s = ei[e], d = ei[E + e], k = ea[e] - 1;
        int dp = d / PSZ, sp = s / PSZ;
        int loc = (d - dp * PSZ) * T + k;
        int posD = atomicAdd(&pd[dp], 1);
        binD[posD] = (loc << 21) | (k << 17) | s;
        int posS = atomicAdd(&ps[sp], 1);
        binS[posS] = (ushort)((s - sp * PSZ) * T + k);
    }
}

__global__ __launch_bounds__(512) void kDE(const int* __restrict__ binD,
                                           const ushort* __restrict__ binS,
                                           const int* __restrict__ partTotD,
                                           const int* __restrict__ partTotS,
                                           int N, int T, int PSZ, int M, int E,
                                           int* __restrict__ rowptr, float* __restrict__ isdD2,
                                           int* __restrict__ ep, float* __restrict__ isdS) {
    __shared__ int cnt[4096];
    __shared__ int part[512];
    __shared__ int sc[256];
    int b = blockIdx.x, tid = threadIdx.x;
    bool isD = b < NP;
    int p = isD ? b : b - NP;
    const int* pt = isD ? partTotD : partTotS;
    if (tid < 256) sc[tid] = pt[tid];
    __syncthreads();
    for (int off = 1; off < 256; off <<= 1) {
        int add = (tid < 256 && tid >= off) ? sc[tid - off] : 0;
        __syncthreads();
        if (tid < 256) sc[tid] += add;
        __syncthreads();
    }
    int b1 = sc[p];
    int b0 = b1 - pt[p];
    __syncthreads();
    int nloc = PSZ * T;
    for (int i = tid; i < nloc; i += 512) cnt[i] = 0;
    __syncthreads();
    if (isD) {
        for (int e = b0 + tid; e < b1; e += 512)
            atomicAdd(&cnt[((unsigned)binD[e]) >> 21], 1);
        __syncthreads();
        int CH = (nloc + 511) / 512;
        int c0 = tid * CH, c1 = min(c0 + CH, nloc);
        int s = 0;
        for (int i = c0; i < c1; i++) s += cnt[i];
        part[tid] = s; __syncthreads();
        for (int off = 1; off < 512; off <<= 1) {
            int add = (tid >= off) ? part[tid - off] : 0;
            __syncthreads(); part[tid] += add; __syncthreads();
        }
        int run = ((tid == 0) ? 0 : part[tid - 1]) + b0;
        int gb_base = p * PSZ * T;
        for (int i = c0; i < c1; i++) {
            int v = cnt[i];
            cnt[i] = run;
            int gb = gb_base + i;
            if (gb < M) {
                rowptr[gb] = run;
                isdD2[gb] = rsqrtf((float)max(v, 1));
            }
            run += v;
        }
        __syncthreads();
        for (int e = b0 + tid; e < b1; e += 512) {
            int v = binD[e];
            int pos = atomicAdd(&cnt[((unsigned)v) >> 21], 1);
            ep[pos] = v & 0x1FFFFF;   // k<<17 | s
        }
        if (p == 0 && tid == 0) rowptr[M] = E;
    } else {
        for (int e = b0 + tid; e < b1; e += 512)
            atomicAdd(&cnt[(int)binS[e]], 1);
        __syncthreads();
        int s0 = p * PSZ;
        for (int i = tid; i < nloc; i += 512) {
            int sl = i / T, k = i - sl * T;
            int snode = s0 + sl;
            if (snode < N) isdS[k * N + snode] = rsqrtf((float)max(cnt[i], 1));
        }
    }
}

// ------- multi-k GEMM: for A = hist[j], compute P[i] = diag(isk_i)*(A @ W_i), i=0..nk-1 -------
// 128 rows/block, A-tile cached in registers across the i-loop (A read from HBM once).

__global__ __launch_bounds__(256) void k_gemm_multi(
        const ushort* __restrict__ A, const ushort* __restrict__ WTb,
        const float* __restrict__ iskb,
        ushort* __restrict__ d0, ushort* __restrict__ d1,
        ushort* __restrict__ d2, ushort* __restrict__ d3,
        int nk, int N) {
    __shared__ ushort lW[128 * 128];   // 32 KB
    int tid = threadIdx.x;
    int wave = tid >> 6;
    int lane = tid & 63;
    int rlo = lane & 15;
    int khi = lane >> 4;
    int r0 = blockIdx.x * 128 + wave * 32;

    int ca[2];
#pragma unroll
    for (int s = 0; s < 2; s++) {
        int r = r0 + s * 16 + rlo;
        ca[s] = r < N ? r : N - 1;
    }
    bf16x8 a[2][4];
#pragma unroll
    for (int s = 0; s < 2; s++)
#pragma unroll
        for (int kk = 0; kk < 4; kk++)
            a[s][kk] = *(const bf16x8*)(A + (size_t)ca[s] * DD + kk * 32 + khi * 8);

#pragma unroll
    for (int i = 0; i < 4; i++) {
        if (i >= nk) break;
        ushort* H = (i == 0) ? d0 : (i == 1) ? d1 : (i == 2) ? d2 : d3;
        const ushort* WT = WTb + (size_t)i * DD * DD;
        const float* isk = iskb + (size_t)i * N;

        __syncthreads();
#pragma unroll
        for (int g8 = 0; g8 < 8; g8++) {
            int g = tid + g8 * 256;
            int row = g >> 4, slot = g & 15;
            bf16x8 v = *(const bf16x8*)(WT + row * DD + slot * 8);
            *(bf16x8*)(lW + row * DD + (slot ^ (row & 7)) * 8) = v;
        }
        __syncthreads();

        f32x4 acc[2][8];
#pragma unroll
        for (int s = 0; s < 2; s++)
#pragma unroll
            for (int j = 0; j < 8; j++) acc[s][j] = (f32x4){0.f, 0.f, 0.f, 0.f};

#pragma unroll
        for (int kk = 0; kk < 4; kk++) {
            int q = kk * 4 + khi;
#pragma unroll
            for (int cg = 0; cg < 8; cg++) {
                int row = cg * 16 + rlo;
                bf16x8 b = *(const bf16x8*)(lW + row * DD + (q ^ (rlo & 7)) * 8);
#pragma unroll
                for (int s = 0; s < 2; s++)
                    acc[s][cg] = __builtin_amdgcn_mfma_f32_16x16x32_bf16(a[s][kk], b, acc[s][cg], 0, 0, 0);
            }
        }

#pragma unroll
        for (int s = 0; s < 2; s++) {
#pragma unroll
            for (int r = 0; r < 4; r++) {
                int row = r0 + s * 16 + khi * 4 + r;
                if (row < N) {
                    float sc = isk[row];
#pragma unroll
                    for (int cg = 0; cg < 8; cg++)
                        H[(size_t)row * DD + cg * 16 + rlo] = (ushort)toBf(sc * acc[s][cg][r]);
                }
            }
        }
    }
}

// ------- fallback batched GEMM (256-row tile): H'_k0 = diag(isk)*(A_k0 @ W_k0) -------

struct APtrs { const ushort* a0; const ushort* a1; const ushort* a2; const ushort* a3; };

__global__ __launch_bounds__(256) void k_gemm_batch(APtrs ap,
                                                    const ushort* __restrict__ WTb,
                                                    const float* __restrict__ iskb,
                                                    ushort* __restrict__ Hb, int N) {
    __shared__ ushort lW[128 * 128];   // 32 KB
    int k0 = blockIdx.y;
    const ushort* A = (k0 == 0) ? ap.a0 : (k0 == 1) ? ap.a1 : (k0 == 2) ? ap.a2 : ap.a3;
    const ushort* WT = WTb + (size_t)k0 * DD * DD;
    const float* isk = iskb + (size_t)k0 * N;
    ushort* H = Hb + (size_t)k0 * N * DD;

    int tid = threadIdx.x;
#pragma unroll
    for (int i = 0; i < 8; i++) {
        int g = tid + i * 256;
        int row = g >> 4, slot = g & 15;
        bf16x8 v = *(const bf16x8*)(WT + row * DD + slot * 8);
        *(bf16x8*)(lW + row * DD + (slot ^ (row & 7)) * 8) = v;
    }
    __syncthreads();

    int wave = tid >> 6;
    int lane = tid & 63;
    int rlo = lane & 15;
    int khi = lane >> 4;
    int r0 = blockIdx.x * 256 + wave * 64;

    f32x4 acc[4][8];
#pragma unroll
    for (int s = 0; s < 4; s++)
#pragma unroll
        for (int j = 0; j < 8; j++) acc[s][j] = (f32x4){0.f, 0.f, 0.f, 0.f};

    int ca[4];
#pragma unroll
    for (int s = 0; s < 4; s++) {
        int r = r0 + s * 16 + rlo;
        ca[s] = r < N ? r : N - 1;
    }

#pragma unroll
    for (int kk = 0; kk < 4; kk++) {
        int d0 = kk * 32 + khi * 8;
        bf16x8 a[4];
#pragma unroll
        for (int s = 0; s < 4; s++)
            a[s] = *(const bf16x8*)(A + (size_t)ca[s] * DD + d0);
        int q = kk * 4 + khi;
#pragma unroll
        for (int cg = 0; cg < 8; cg++) {
            int row = cg * 16 + rlo;
            bf16x8 b = *(const bf16x8*)(lW + row * DD + (q ^ (rlo & 7)) * 8);
#pragma unroll
            for (int s = 0; s < 4; s++)
                acc[s][cg] = __builtin_amdgcn_mfma_f32_16x16x32_bf16(a[s], b, acc[s][cg], 0, 0, 0);
        }
    }

#pragma unroll
    for (int s = 0; s < 4; s++) {
#pragma unroll
        for (int r = 0; r < 4; r++) {
            int row = r0 + s * 16 + khi * 4 + r;
            if (row < N) {
                float sc = isk[row];
#pragma unroll
                for (int cg = 0; cg < 8; cg++)
                    H[(size_t)row * DD + cg * 16 + rlo] = (ushort)toBf(sc * acc[s][cg][r]);
            }
        }
    }
}

// ------- per-layer agg: gather-sum; slice location via per-k byte bases (sb) -------

__device__ __forceinline__ float selw(float w0, float w1, float w2, float w3, int k) {
    float a = (k & 1) ? w1 : w0;
    float b = (k & 1) ? w3 : w2;
    return (k & 2) ? b : a;
}
__device__ __forceinline__ int selwi(int a, int b, int c, int d, int k) {
    int x = (k & 1) ? b : a;
    int y = (k & 1) ? d : c;
    return (k & 2) ? y : x;
}

__global__ __launch_bounds__(256) void k_agg_fin(
        const ushort* __restrict__ H,        // product region base
        int4 sb,                             // per-k slice base BYTE offsets within H
        const int* __restrict__ ep,          // packed payloads (k<<17|s), (dst,k)-bucket order
        const int* __restrict__ rp,          // M+1 rowptr, bucket = d*T+k
        const float* __restrict__ isdD2,     // M, d*T+k
        const float* __restrict__ nu, int t, int T, int nk,
        const ushort* __restrict__ hp,       // residual input (bf16)
        ushort* __restrict__ hnB,            // bf16 hist output (t < T-1)
        float* __restrict__ outF,            // f32 output (t == T-1), else null
        int N) {
    int node = (blockIdx.x * blockDim.x + threadIdx.x) >> 5;
    if (node >= N) return;
    int lane = threadIdx.x & 31;
    int rbase = node * T;
    int b0 = rp[rbase], b1 = rp[rbase + nk];

    float w0 = nu[t] * isdD2[rbase];
    float w1 = (1 < nk) ? nu[T + t]     * isdD2[rbase + 1] : 0.f;
    float w2 = (2 < nk) ? nu[2 * T + t] * isdD2[rbase + 2] : 0.f;
    float w3 = (3 < nk) ? nu[3 * T + t] * isdD2[rbase + 3] : 0.f;

    const char* Hc = (const char*)H;
    unsigned lb = (unsigned)lane << 3;   // byte offset of this lane's 8B within a 256B row

    float sx = 0.f, sy = 0.f, sz = 0.f, sw = 0.f;
    int e = b0;

#define DEC(P, O, C) { \
    int kk_ = (P) >> 17; \
    O = (unsigned)selwi(sb.x, sb.y, sb.z, sb.w, kk_) + (((((unsigned)(P)) & 0x1FFFFu) << 8) | lb); \
    C = selw(w0, w1, w2, w3, kk_); }

#define ACC(G, C) { \
    float f0 = __uint_as_float((G).x << 16); \
    float f1 = __uint_as_float((G).x & 0xffff0000u); \
    float f2 = __uint_as_float((G).y << 16); \
    float f3 = __uint_as_float((G).y & 0xffff0000u); \
    sx = fmaf((C), f0, sx); sy = fmaf((C), f1, sy); \
    sz = fmaf((C), f2, sz); sw = fmaf((C), f3, sw); }

    for (; e + 7 < b1; e += 8) {
        int p0 = ep[e],     p1 = ep[e + 1], p2 = ep[e + 2], p3 = ep[e + 3];
        int p4 = ep[e + 4], p5 = ep[e + 5], p6 = ep[e + 6], p7 = ep[e + 7];
        unsigned o0, o1, o2, o3, o4, o5, o6, o7;
        float c0, c1, c2, c3, c4, c5, c6, c7;
        DEC(p0, o0, c0) DEC(p1, o1, c1) DEC(p2, o2, c2) DEC(p3, o3, c3)
        DEC(p4, o4, c4) DEC(p5, o5, c5) DEC(p6, o6, c6) DEC(p7, o7, c7)
        uint2 g0 = *(const uint2*)(Hc + o0);
        uint2 g1 = *(const uint2*)(Hc + o1);
        uint2 g2 = *(const uint2*)(Hc + o2);
        uint2 g3 = *(const uint2*)(Hc + o3);
        uint2 g4 = *(const uint2*)(Hc + o4);
        uint2 g5 = *(const uint2*)(Hc + o5);
        uint2 g6 = *(const uint2*)(Hc + o6);
        uint2 g7 = *(const uint2*)(Hc + o7);
        ACC(g0, c0) ACC(g1, c1) ACC(g2, c2) ACC(g3, c3)
        ACC(g4, c4) ACC(g5, c5) ACC(g6, c6) ACC(g7, c7)
    }
    if (e + 3 < b1) {
        int p0 = ep[e], p1 = ep[e + 1], p2 = ep[e + 2], p3 = ep[e + 3];
        unsigned o0, o1, o2, o3;
        float c0, c1, c2, c3;
        DEC(p0, o0, c0) DEC(p1, o1, c1) DEC(p2, o2, c2) DEC(p3, o3, c3)
        uint2 g0 = *(const uint2*)(Hc + o0);
        uint2 g1 = *(const uint2*)(Hc + o1);
        uint2 g2 = *(const uint2*)(Hc + o2);
        uint2 g3 = *(const uint2*)(Hc + o3);
        ACC(g0, c0) ACC(g1, c1) ACC(g2, c2) ACC(g3, c3)
        e += 4;
    }
    for (; e < b1; e++) {
        int p0 = ep[e];
        unsigned o0; float c0;
        DEC(p0, o0, c0)
        uint2 g0 = *(const uint2*)(Hc + o0);
        ACC(g0, c0)
    }
#undef DEC
#undef ACC

    unsigned nodeOff = ((unsigned)node << 8) | lb;
    uint2 hv = *(const uint2*)((const char*)hp + nodeOff);
    float vx = __uint_as_float(hv.x << 16)         + fmaxf(sx, 0.f);
    float vy = __uint_as_float(hv.x & 0xffff0000u) + fmaxf(sy, 0.f);
    float vz = __uint_as_float(hv.y << 16)         + fmaxf(sz, 0.f);
    float vw = __uint_as_float(hv.y & 0xffff0000u) + fmaxf(sw, 0.f);
    float ss = vx * vx + vy * vy + vz * vz + vw * vw;
#pragma unroll
    for (int off = 16; off; off >>= 1) ss += __shfl_xor(ss, off, 32);
    float inv = 1.f / fmaxf(sqrtf(ss), 1e-12f);
    vx *= inv; vy *= inv; vz *= inv; vw *= inv;
    if (outF) {
        f4 o; o.x = vx; o.y = vy; o.z = vz; o.w = vw;
        *(f4*)((char*)outF + (((size_t)node << 9) | ((size_t)lane << 4))) = o;
    } else {
        uint lo = ((unsigned)(unsigned short)toBf(vx)) | (((unsigned)(unsigned short)toBf(vy)) << 16);
        uint hi = ((unsigned)(unsigned short)toBf(vz)) | (((unsigned)(unsigned short)toBf(vw)) << 16);
        uint2 ob; ob.x = lo; ob.y = hi;
        *(uint2*)((char*)hnB + nodeOff) = ob;
    }
}

// eager-path fingerprint: extra dispatch -> 13 dispatches/iter vs 12 serial
__global__ void kMark() {}

// ---------------- driver ----------------

extern "C" void kernel_launch(void* const* d_in, const int* in_sizes, int n_in,
                              void* d_out, int out_size, void* d_ws, size_t ws_size,
                              hipStream_t stream) {
    const float* x  = (const float*)d_in[0];
    const int*   ei = (const int*)d_in[1];
    const int*   ea = (const int*)d_in[2];
    const float* W  = (const float*)d_in[3];
    const float* nu = (const float*)d_in[4];
    float* out = (float*)d_out;

    int N = in_sizes[0] / DD;
    int E = in_sizes[1] / 2;
    int T = in_sizes[3] / (DD * DD);
    int M = T * N;
    size_t ND = (size_t)N * DD;

    int PSZ = (N + NP - 1) / NP;
    if (PSZ * T > 2048) return;          // payload loc bits + LDS counters
    if (T > 4 || N > 131072) return;     // payload k/s bits
    int nbA = (E + EB - 1) / EB;
    if (nbA > 512) return;

    size_t reqSerial = sizeof(float) * 2 * (size_t)M
                     + sizeof(ushort) * ((size_t)(4 + 4) * ND + (size_t)T * DD * DD)
                     + sizeof(int) * ((size_t)M + 1 + (size_t)E + 64);
    size_t reqEager  = reqSerial + sizeof(ushort) * 2 * ND;   // 6 slices vs 4
    if (ws_size < reqSerial) return;
    bool eager = (T == 4) && (ws_size >= reqEager);
    size_t Lslices = eager ? 6 : 4;

    // workspace layout
    float*  isdS  = (float*)d_ws;            // M f32 (k-major, rsqrt deg_src)
    float*  isdD2 = isdS + M;                // M f32 (dst-major d*T+k, rsqrt deg_dst)
    ushort* xb    = (ushort*)(isdD2 + M);    // ND bf16
    ushort* h1b   = xb + ND;
    ushort* h2b   = h1b + ND;
    ushort* h3b   = h2b + ND;
    ushort* Lr    = h3b + ND;                // product region: 6*ND (eager) or 4*ND (serial)
    ushort* WT    = Lr + Lslices * ND;       // T*128*128 bf16
    int* rowptr   = (int*)(WT + (size_t)T * DD * DD);  // M+1
    int* ep       = rowptr + M + 1;          // E
    // setup scratch aliases Lr (setup strictly precedes all product writes)
    int*    binD     = (int*)Lr;                         // E
    ushort* binS     = (ushort*)(binD + E);              // E
    int*    cntB_D   = (int*)(binS + (((size_t)E + 1) & ~(size_t)1));
    int*    cntB_S   = cntB_D + NP * nbA;
    int*    partTotD = cntB_S + NP * nbA;
    int*    partTotS = partTotD + NP;

    size_t scratch = 4 * (size_t)E + 2 * ((size_t)E + 2)
                   + sizeof(int) * (2 * (size_t)NP * nbA + 2 * NP + 16);
    if (scratch > sizeof(ushort) * Lslices * ND) return;

    int totW = T * DD * DD;
    int nPW = (totW + 1023) / 1024;
    int n8 = (int)(ND / 8);
    int nCvt = (n8 + 1023) / 1024;

    kAF<<<nbA + nPW + nCvt, 1024, 0, stream>>>(ei, E, PSZ, nbA, cntB_D, cntB_S,
                                               W, WT, totW, nPW, x, xb, n8);
    kB1<<<2 * NP, 512, 0, stream>>>(cntB_D, cntB_S, nbA, partTotD, partTotS);
    kC<<<nbA, 1024, 0, stream>>>(ei, ea, E, N, T, PSZ, nbA, cntB_D, cntB_S,
                                 partTotD, partTotS, binD, binS);
    kDE<<<2 * NP, 512, 0, stream>>>(binD, binS, partTotD, partTotS,
                                    N, T, PSZ, M, E, rowptr, isdD2, ep, isdS);

    const ushort* histB[4] = {xb, h1b, h2b, h3b};
    int nodeBlocks = ((size_t)N * 32 + 255) / 256;
    int rowBytes = N * 256;   // bytes per slice (N rows x 256 B)

    if (eager) {
        kMark<<<1, 64, 0, stream>>>();
        // fixed 6-slot schedule (liveness-packed)
        const int dstSlot[4][4] = {{0, 1, 2, 3}, {4, 5, 0, 0}, {1, 4, 0, 0}, {2, 0, 0, 0}};
        const int aggSlot[4][4] = {{0, 0, 0, 0}, {4, 1, 0, 0}, {1, 5, 2, 0}, {2, 4, 0, 3}};
        int gb128 = (N + 127) / 128;
        for (int t = 0; t < 4; t++) {
            int nk = 4 - t;
            ushort* d0 = Lr + (size_t)dstSlot[t][0] * ND;
            ushort* d1 = (nk > 1) ? Lr + (size_t)dstSlot[t][1] * ND : d0;
            ushort* d2 = (nk > 2) ? Lr + (size_t)dstSlot[t][2] * ND : d0;
            ushort* d3 = (nk > 3) ? Lr + (size_t)dstSlot[t][3] * ND : d0;
            k_gemm_multi<<<gb128, 256, 0, stream>>>(histB[t], WT, isdS,
                                                    d0, d1, d2, d3, nk, N);
            int4 sb;
            sb.x = aggSlot[t][0] * rowBytes;
            sb.y = aggSlot[t][1] * rowBytes;
            sb.z = aggSlot[t][2] * rowBytes;
            sb.w = aggSlot[t][3] * rowBytes;
            bool lastL = (t == 3);
            k_agg_fin<<<nodeBlocks, 256, 0, stream>>>(Lr, sb, ep, rowptr, isdD2,
                                                      nu, t, T, t + 1, histB[t],
                                                      lastL ? nullptr : (ushort*)histB[t + 1],
                                                      lastL ? out : nullptr, N);
        }
    } else {
        int gb256 = (N + 255) / 256;
        int4 sb;
        sb.x = 0; sb.y = rowBytes; sb.z = 2 * rowBytes; sb.w = 3 * rowBytes;
        for (int t = 0; t < T; t++) {
            APtrs ap;
            ap.a0 = histB[t];
            ap.a1 = (t >= 1) ? histB[t - 1] : histB[0];
            ap.a2 = (t >= 2) ? histB[t - 2] : histB[0];
            ap.a3 = (t >= 3) ? histB[t - 3] : histB[0];
            dim3 grid(gb256, t + 1);
            k_gemm_batch<<<grid, 256, 0, stream>>>(ap, WT, isdS, Lr, N);
            bool lastL = (t == T - 1);
            k_agg_fin<<<nodeBlocks, 256, 0, stream>>>(Lr, sb, ep, rowptr, isdD2,
                                                      nu, t, T, t + 1, histB[t],
                                                      lastL ? nullptr : (ushort*)histB[t + 1],
                                                      lastL ? out : nullptr, N);
        }
    }
}

// Round 10
// 407.566 us; speedup vs baseline: 1.0042x; 1.0042x over previous
//
#include <hip/hip_runtime.h>

#define DD 128   // feature dim
#define NP 256   // node partitions
#define EB 4096  // edges per binning block

typedef float4 f4;
typedef __attribute__((ext_vector_type(8))) short bf16x8;
typedef __attribute__((ext_vector_type(4))) float f32x4;

__device__ __forceinline__ short toBf(float f) {
    unsigned u = __float_as_uint(f);
    u += 0x7fff + ((u >> 16) & 1);   // RNE
    return (short)(u >> 16);
}

// ---------------- setup: LDS-binned counting sort (no global atomics) ----------------
// payload packing (32-bit): [31:21] local bucket (dloc*T+k, <2048) | [20:19] k | [18:0] row = k*N+s

// fused: blocks [0,nbA) = histogram role; [nbA,nbA+nPW) = prepW; rest = cvt
__global__ __launch_bounds__(1024) void kAF(const int* __restrict__ ei, int E, int PSZ, int nbA,
                                            int* __restrict__ cntB_D, int* __restrict__ cntB_S,
                                            const float* __restrict__ W, ushort* __restrict__ WT,
                                            int totW, int nPW,
                                            const float* __restrict__ x, ushort* __restrict__ xb,
                                            int n8) {
    __shared__ int hd[NP], hs[NP];
    int tid = threadIdx.x, b = blockIdx.x;
    if (b < nbA) {
        if (tid < NP) { hd[tid] = 0; hs[tid] = 0; }
        __syncthreads();
        int base = b * EB;
        int lim = min(base + EB, E);
        for (int e = base + tid; e < lim; e += 1024) {
            int s = ei[e], d = ei[E + e];
            atomicAdd(&hs[s / PSZ], 1);
            atomicAdd(&hd[d / PSZ], 1);
        }
        __syncthreads();
        if (tid < NP) {
            cntB_D[tid * nbA + b] = hd[tid];
            cntB_S[tid * nbA + b] = hs[tid];
        }
    } else if (b < nbA + nPW) {
        int i = (b - nbA) * 1024 + tid;
        if (i < totW) {
            int k = i >> 14, rem = i & 16383, j = rem >> 7, d = rem & 127;
            WT[i] = (ushort)toBf(W[(size_t)k * 16384 + (size_t)d * DD + j]);  // WT[k][j][d] = W[k][d][j]
        }
    } else {
        int i = (b - nbA - nPW) * 1024 + tid;
        if (i < n8) {
            const f4* q = (const f4*)(x + (size_t)i * 8);
            f4 lo = q[0], hi = q[1];
            bf16x8 r;
            r[0] = toBf(lo.x); r[1] = toBf(lo.y); r[2] = toBf(lo.z); r[3] = toBf(lo.w);
            r[4] = toBf(hi.x); r[5] = toBf(hi.y); r[6] = toBf(hi.z); r[7] = toBf(hi.w);
            *(bf16x8*)(xb + (size_t)i * 8) = r;
        }
    }
}

// kB1: per-partition local exclusive scan of nbA per-block counters (one block per partition,
// D-role for b<NP, S-role for b>=NP); emits partition totals.
__global__ __launch_bounds__(512) void kB1(int* __restrict__ cntB_D, int* __restrict__ cntB_S,
                                           int nbA,
                                           int* __restrict__ partTotD, int* __restrict__ partTotS) {
    __shared__ int sh[512];
    int b = blockIdx.x, tid = threadIdx.x;
    int* cntB = (b < NP) ? cntB_D : cntB_S;
    int* partTot = (b < NP) ? partTotD : partTotS;
    int p = (b < NP) ? b : b - NP;
    int v = (tid < nbA) ? cntB[p * nbA + tid] : 0;
    sh[tid] = v; __syncthreads();
    for (int off = 1; off < 512; off <<= 1) {
        int add = (tid >= off) ? sh[tid - off] : 0;
        __syncthreads(); sh[tid] += add; __syncthreads();
    }
    if (tid < nbA) cntB[p * nbA + tid] = sh[tid] - v;   // local exclusive prefix
    if (tid == 511) partTot[p] = sh[511];
}

__global__ __launch_bounds__(1024) void kC(const int* __restrict__ ei, const int* __restrict__ ea,
                                           int E, int N, int T, int PSZ, int nbA,
                                           const int* __restrict__ cntB_D, const int* __restrict__ cntB_S,
                                           const int* __restrict__ partTotD,
                                           const int* __restrict__ partTotS,
                                           int* __restrict__ binD, ushort* __restrict__ binS) {
    __shared__ int pd[NP], ps[NP];
    __shared__ int sc[512];
    int tid = threadIdx.x, b = blockIdx.x;
    // segmented inclusive scan: lanes 0-255 = partTotD, 256-511 = partTotS
    if (tid < 512) sc[tid] = (tid < 256) ? partTotD[tid] : partTotS[tid - 256];
    __syncthreads();
    for (int off = 1; off < 256; off <<= 1) {
        int add = 0;
        if (tid < 512 && (tid & 255) >= off) add = sc[tid - off];
        __syncthreads();
        if (tid < 512) sc[tid] += add;
        __syncthreads();
    }
    if (tid < NP) {
        pd[tid] = cntB_D[tid * nbA + b] + (sc[tid] - partTotD[tid]);
        ps[tid] = cntB_S[tid * nbA + b] + (sc[tid + 256] - partTotS[tid]);
    }
    __syncthreads();
    int base = b * EB;
    int lim = min(base + EB, E);
    for (int e = base + tid; e < lim; e += 1024) {
        int s = ei[e], d = ei[E + e], k = ea[e] - 1;
        int dp = d / PSZ, sp = s / PSZ;
        int loc = (d - dp * PSZ) * T + k;
        int posD = atomicAdd(&pd[dp], 1);
        binD[posD] = (loc << 21) | (k << 19) | (k * N + s);
        int posS = atomicAdd(&ps[sp], 1);
        binS[posS] = (ushort)((s - sp * PSZ) * T + k);
    }
}

// fused kD (dst buckets -> rowptr/isdD2/ep) + kE (src degree -> isdS):
// blocks [0,NP) do D-role partition p=b; blocks [NP,2*NP) do S-role partition p=b-NP.
__global__ __launch_bounds__(512) void kDE(const int* __restrict__ binD,
                                           const ushort* __restrict__ binS,
                                           const int* __restrict__ partTotD,
                                           const int* __restrict__ partTotS,
                                           int N, int T, int PSZ, int M, int E,
                                           int* __restrict__ rowptr, float* __restrict__ isdD2,
                                           int* __restrict__ ep, float* __restrict__ isdS) {
    __shared__ int cnt[4096];
    __shared__ int part[512];
    __shared__ int sc[256];
    int b = blockIdx.x, tid = threadIdx.x;
    bool isD = b < NP;
    int p = isD ? b : b - NP;
    const int* pt = isD ? partTotD : partTotS;
    if (tid < 256) sc[tid] = pt[tid];
    __syncthreads();
    for (int off = 1; off < 256; off <<= 1) {
        int add = (tid < 256 && tid >= off) ? sc[tid - off] : 0;
        __syncthreads();
        if (tid < 256) sc[tid] += add;
        __syncthreads();
    }
    int b1 = sc[p];
    int b0 = b1 - pt[p];
    __syncthreads();
    int nloc = PSZ * T;
    for (int i = tid; i < nloc; i += 512) cnt[i] = 0;
    __syncthreads();
    if (isD) {
        for (int e = b0 + tid; e < b1; e += 512)
            atomicAdd(&cnt[((unsigned)binD[e]) >> 21], 1);
        __syncthreads();
        int CH = (nloc + 511) / 512;
        int c0 = tid * CH, c1 = min(c0 + CH, nloc);
        int s = 0;
        for (int i = c0; i < c1; i++) s += cnt[i];
        part[tid] = s; __syncthreads();
        for (int off = 1; off < 512; off <<= 1) {
            int add = (tid >= off) ? part[tid - off] : 0;
            __syncthreads(); part[tid] += add; __syncthreads();
        }
        int run = ((tid == 0) ? 0 : part[tid - 1]) + b0;
        int gb_base = p * PSZ * T;
        for (int i = c0; i < c1; i++) {
            int v = cnt[i];
            cnt[i] = run;
            int gb = gb_base + i;
            if (gb < M) {
                rowptr[gb] = run;
                isdD2[gb] = rsqrtf((float)max(v, 1));
            }
            run += v;
        }
        __syncthreads();
        for (int e = b0 + tid; e < b1; e += 512) {
            int v = binD[e];
            int pos = atomicAdd(&cnt[((unsigned)v) >> 21], 1);
            ep[pos] = v & 0x1FFFFF;
        }
        if (p == 0 && tid == 0) rowptr[M] = E;
    } else {
        for (int e = b0 + tid; e < b1; e += 512)
            atomicAdd(&cnt[(int)binS[e]], 1);
        __syncthreads();
        int s0 = p * PSZ;
        for (int i = tid; i < nloc; i += 512) {
            int sl = i / T, k = i - sl * T;
            int snode = s0 + sl;
            if (snode < N) isdS[k * N + snode] = rsqrtf((float)max(cnt[i], 1));
        }
    }
}

// ------- batched GEMM: H'_k0[N,128](bf16) = diag(isk) * (A_k0 @ W_k0), MFMA -------
// W staged in LDS (32 KB) with 16B-granule XOR swizzle; 256 rows/block, 64 rows/wave.

struct APtrs { const ushort* a0; const ushort* a1; const ushort* a2; const ushort* a3; };

__global__ __launch_bounds__(256) void k_gemm_batch(APtrs ap,
                                                    const ushort* __restrict__ WTb,
                                                    const float* __restrict__ iskb,
                                                    ushort* __restrict__ Hb, int N) {
    __shared__ ushort lW[128 * 128];   // 32 KB
    int k0 = blockIdx.y;
    const ushort* A = (k0 == 0) ? ap.a0 : (k0 == 1) ? ap.a1 : (k0 == 2) ? ap.a2 : ap.a3;
    const ushort* WT = WTb + (size_t)k0 * DD * DD;
    const float* isk = iskb + (size_t)k0 * N;
    ushort* H = Hb + (size_t)k0 * N * DD;

    int tid = threadIdx.x;
#pragma unroll
    for (int i = 0; i < 8; i++) {
        int g = tid + i * 256;
        int row = g >> 4, slot = g & 15;
        bf16x8 v = *(const bf16x8*)(WT + row * DD + slot * 8);
        *(bf16x8*)(lW + row * DD + (slot ^ (row & 7)) * 8) = v;
    }
    __syncthreads();

    int wave = tid >> 6;
    int lane = tid & 63;
    int rlo = lane & 15;       // A row within strip / C col within 16
    int khi = lane >> 4;       // 0..3
    int r0 = blockIdx.x * 256 + wave * 64;

    f32x4 acc[4][8];
#pragma unroll
    for (int s = 0; s < 4; s++)
#pragma unroll
        for (int j = 0; j < 8; j++) acc[s][j] = (f32x4){0.f, 0.f, 0.f, 0.f};

    int ca[4];
#pragma unroll
    for (int s = 0; s < 4; s++) {
        int r = r0 + s * 16 + rlo;
        ca[s] = r < N ? r : N - 1;
    }

#pragma unroll
    for (int kk = 0; kk < 4; kk++) {
        int d0 = kk * 32 + khi * 8;
        bf16x8 a[4];
#pragma unroll
        for (int s = 0; s < 4; s++)
            a[s] = *(const bf16x8*)(A + (size_t)ca[s] * DD + d0);
        int q = kk * 4 + khi;   // 16B slot index along d
#pragma unroll
        for (int cg = 0; cg < 8; cg++) {
            int row = cg * 16 + rlo;
            bf16x8 b = *(const bf16x8*)(lW + row * DD + (q ^ (rlo & 7)) * 8);
#pragma unroll
            for (int s = 0; s < 4; s++)
                acc[s][cg] = __builtin_amdgcn_mfma_f32_16x16x32_bf16(a[s], b, acc[s][cg], 0, 0, 0);
        }
    }

#pragma unroll
    for (int s = 0; s < 4; s++) {
#pragma unroll
        for (int r = 0; r < 4; r++) {
            int row = r0 + s * 16 + khi * 4 + r;
            if (row < N) {
                float sc = isk[row];
#pragma unroll
                for (int cg = 0; cg < 8; cg++)
                    H[(size_t)row * DD + cg * 16 + rlo] = (ushort)toBf(sc * acc[s][cg][r]);
            }
        }
    }
}

// ------- per-layer agg: gather-sum over contiguous segment; out = l2norm(hist + relu(acc)) -------

__device__ __forceinline__ float selw(float w0, float w1, float w2, float w3, int k) {
    float a = (k & 1) ? w1 : w0;
    float b = (k & 1) ? w3 : w2;
    return (k & 2) ? b : a;
}

__global__ __launch_bounds__(256) void k_agg_fin(
        const ushort* __restrict__ H,        // T*N rows of 128 bf16, row idx = k*N+src
        const int* __restrict__ ep,          // packed payloads (k<<19|row), (dst,k)-bucket order
        const int* __restrict__ rp,          // M+1 rowptr, bucket = d*T+k
        const float* __restrict__ isdD2,     // M, d*T+k
        const float* __restrict__ nu, int t, int T, int nk,
        const ushort* __restrict__ hp,       // residual input (bf16)
        ushort* __restrict__ hnB,            // bf16 hist output (t < T-1)
        float* __restrict__ outF,            // f32 output (t == T-1), else null
        int N) {
    int node = (blockIdx.x * blockDim.x + threadIdx.x) >> 5;
    if (node >= N) return;
    int lane = threadIdx.x & 31;
    int rbase = node * T;
    int b0 = rp[rbase], b1 = rp[rbase + nk];

    float w0 = nu[t] * isdD2[rbase];
    float w1 = (1 < nk) ? nu[T + t]     * isdD2[rbase + 1] : 0.f;
    float w2 = (2 < nk) ? nu[2 * T + t] * isdD2[rbase + 2] : 0.f;
    float w3 = (3 < nk) ? nu[3 * T + t] * isdD2[rbase + 3] : 0.f;

    const char* Hc = (const char*)H;
    unsigned lb = (unsigned)lane << 3;   // byte offset of this lane's 8B within a 256B row

    float sx = 0.f, sy = 0.f, sz = 0.f, sw = 0.f;
    int e = b0;

#define DEC(P, O, C) \
    O = ((((unsigned)(P)) & 0x7FFFFu) << 8) | lb; \
    C = selw(w0, w1, w2, w3, (P) >> 19);

#define ACC(G, C) { \
    float f0 = __uint_as_float((G).x << 16); \
    float f1 = __uint_as_float((G).x & 0xffff0000u); \
    float f2 = __uint_as_float((G).y << 16); \
    float f3 = __uint_as_float((G).y & 0xffff0000u); \
    sx = fmaf((C), f0, sx); sy = fmaf((C), f1, sy); \
    sz = fmaf((C), f2, sz); sw = fmaf((C), f3, sw); }

    // 8-deep main loop: 8 payload loads, then 8 gathers in flight (2 KB/group)
    for (; e + 7 < b1; e += 8) {
        int p0 = ep[e],     p1 = ep[e + 1], p2 = ep[e + 2], p3 = ep[e + 3];
        int p4 = ep[e + 4], p5 = ep[e + 5], p6 = ep[e + 6], p7 = ep[e + 7];
        unsigned o0, o1, o2, o3, o4, o5, o6, o7;
        float c0, c1, c2, c3, c4, c5, c6, c7;
        DEC(p0, o0, c0) DEC(p1, o1, c1) DEC(p2, o2, c2) DEC(p3, o3, c3)
        DEC(p4, o4, c4) DEC(p5, o5, c5) DEC(p6, o6, c6) DEC(p7, o7, c7)
        uint2 g0 = *(const uint2*)(Hc + o0);
        uint2 g1 = *(const uint2*)(Hc + o1);
        uint2 g2 = *(const uint2*)(Hc + o2);
        uint2 g3 = *(const uint2*)(Hc + o3);
        uint2 g4 = *(const uint2*)(Hc + o4);
        uint2 g5 = *(const uint2*)(Hc + o5);
        uint2 g6 = *(const uint2*)(Hc + o6);
        uint2 g7 = *(const uint2*)(Hc + o7);
        ACC(g0, c0) ACC(g1, c1) ACC(g2, c2) ACC(g3, c3)
        ACC(g4, c4) ACC(g5, c5) ACC(g6, c6) ACC(g7, c7)
    }
    // 4-deep tier
    if (e + 3 < b1) {
        int p0 = ep[e], p1 = ep[e + 1], p2 = ep[e + 2], p3 = ep[e + 3];
        unsigned o0, o1, o2, o3;
        float c0, c1, c2, c3;
        DEC(p0, o0, c0) DEC(p1, o1, c1) DEC(p2, o2, c2) DEC(p3, o3, c3)
        uint2 g0 = *(const uint2*)(Hc + o0);
        uint2 g1 = *(const uint2*)(Hc + o1);
        uint2 g2 = *(const uint2*)(Hc + o2);
        uint2 g3 = *(const uint2*)(Hc + o3);
        ACC(g0, c0) ACC(g1, c1) ACC(g2, c2) ACC(g3, c3)
        e += 4;
    }
    // scalar tail
    for (; e < b1; e++) {
        int p0 = ep[e];
        unsigned o0; float c0;
        DEC(p0, o0, c0)
        uint2 g0 = *(const uint2*)(Hc + o0);
        ACC(g0, c0)
    }
#undef DEC
#undef ACC

    unsigned nodeOff = ((unsigned)node << 8) | lb;
    uint2 hv = *(const uint2*)((const char*)hp + nodeOff);
    float vx = __uint_as_float(hv.x << 16)         + fmaxf(sx, 0.f);
    float vy = __uint_as_float(hv.x & 0xffff0000u) + fmaxf(sy, 0.f);
    float vz = __uint_as_float(hv.y << 16)         + fmaxf(sz, 0.f);
    float vw = __uint_as_float(hv.y & 0xffff0000u) + fmaxf(sw, 0.f);
    float ss = vx * vx + vy * vy + vz * vz + vw * vw;
#pragma unroll
    for (int off = 16; off; off >>= 1) ss += __shfl_xor(ss, off, 32);
    float inv = 1.f / fmaxf(sqrtf(ss), 1e-12f);
    vx *= inv; vy *= inv; vz *= inv; vw *= inv;
    if (outF) {
        f4 o; o.x = vx; o.y = vy; o.z = vz; o.w = vw;
        *(f4*)((char*)outF + (((size_t)node << 9) | ((size_t)lane << 4))) = o;
    } else {
        uint lo = ((unsigned)(unsigned short)toBf(vx)) | (((unsigned)(unsigned short)toBf(vy)) << 16);
        uint hi = ((unsigned)(unsigned short)toBf(vz)) | (((unsigned)(unsigned short)toBf(vw)) << 16);
        uint2 ob; ob.x = lo; ob.y = hi;
        *(uint2*)((char*)hnB + nodeOff) = ob;
    }
}

// ---------------- driver ----------------

extern "C" void kernel_launch(void* const* d_in, const int* in_sizes, int n_in,
                              void* d_out, int out_size, void* d_ws, size_t ws_size,
                              hipStream_t stream) {
    const float* x  = (const float*)d_in[0];
    const int*   ei = (const int*)d_in[1];
    const int*   ea = (const int*)d_in[2];
    const float* W  = (const float*)d_in[3];
    const float* nu = (const float*)d_in[4];
    float* out = (float*)d_out;

    int N = in_sizes[0] / DD;
    int E = in_sizes[1] / 2;
    int T = in_sizes[3] / (DD * DD);
    int M = T * N;
    size_t ND = (size_t)N * DD;

    int PSZ = (N + NP - 1) / NP;          // nodes per partition
    if (PSZ * T > 2048) return;           // payload loc-bits + LDS counter budget guard
    if ((long)T * N > (1L << 19)) return; // payload row-bits guard
    int nbA = (E + EB - 1) / EB;          // binning blocks
    if (nbA > 512) return;                // kB1 single-pass scan guard

    // workspace layout
    float*  isdS  = (float*)d_ws;            // M f32 (k-major, rsqrt deg_src)
    float*  isdD2 = isdS + M;                // M f32 (dst-major d*T+k, rsqrt deg_dst)
    ushort* xb    = (ushort*)(isdD2 + M);    // ND bf16
    ushort* h1b   = xb + ND;                 // ND bf16
    ushort* h2b   = h1b + ND;                // ND bf16
    ushort* h3b   = h2b + ND;                // ND bf16
    ushort* Hb    = h3b + ND;                // T*ND bf16 (pre-scaled H'_k)
    ushort* WT    = Hb + (size_t)T * ND;     // T*128*128 bf16
    int* rowptr   = (int*)(WT + (size_t)T * DD * DD);  // M+1
    int* ep       = rowptr + M + 1;          // E
    // setup scratch aliases Hb (setup strictly precedes GEMM writes)
    int*    binD     = (int*)Hb;                         // E
    ushort* binS     = (ushort*)(binD + E);              // E
    int*    cntB_D   = (int*)(binS + (((size_t)E + 1) & ~(size_t)1));  // NP*nbA
    int*    cntB_S   = cntB_D + NP * nbA;                // NP*nbA
    int*    partTotD = cntB_S + NP * nbA;                // NP
    int*    partTotS = partTotD + NP;                    // NP

    size_t req = sizeof(float) * 2 * (size_t)M
               + sizeof(ushort) * ((size_t)(4 + T) * ND + (size_t)T * DD * DD)
               + sizeof(int) * ((size_t)M + 1 + (size_t)E + 64);
    if (ws_size < req) return;
    size_t scratch = 4 * (size_t)E + 2 * ((size_t)E + 2)
                   + sizeof(int) * (2 * (size_t)NP * nbA + 2 * NP + 16);
    if (scratch > sizeof(ushort) * (size_t)T * ND) return;

    int totW = T * DD * DD;
    int nPW = (totW + 1023) / 1024;
    int n8 = (int)(ND / 8);
    int nCvt = (n8 + 1023) / 1024;

    kAF<<<nbA + nPW + nCvt, 1024, 0, stream>>>(ei, E, PSZ, nbA, cntB_D, cntB_S,
                                               W, WT, totW, nPW, x, xb, n8);
    kB1<<<2 * NP, 512, 0, stream>>>(cntB_D, cntB_S, nbA, partTotD, partTotS);
    kC<<<nbA, 1024, 0, stream>>>(ei, ea, E, N, T, PSZ, nbA, cntB_D, cntB_S,
                                 partTotD, partTotS, binD, binS);
    kDE<<<2 * NP, 512, 0, stream>>>(binD, binS, partTotD, partTotS,
                                    N, T, PSZ, M, E, rowptr, isdD2, ep, isdS);

    const ushort* histB[4] = {xb, h1b, h2b, h3b};

    int nodeBlocks = ((size_t)N * 32 + 255) / 256;
    int gemmBlocks = (N + 255) / 256;

    for (int t = 0; t < T; t++) {
        APtrs ap;
        ap.a0 = histB[t];
        ap.a1 = (t >= 1) ? histB[t - 1] : histB[0];
        ap.a2 = (t >= 2) ? histB[t - 2] : histB[0];
        ap.a3 = (t >= 3) ? histB[t - 3] : histB[0];
        dim3 grid(gemmBlocks, t + 1);
        k_gemm_batch<<<grid, 256, 0, stream>>>(ap, WT, isdS, Hb, N);

        bool lastL = (t == T - 1);
        k_agg_fin<<<nodeBlocks, 256, 0, stream>>>(Hb, ep, rowptr, isdD2,
                                                  nu, t, T, t + 1, histB[t],
                                                  lastL ? nullptr : (ushort*)histB[t + 1],
                                                  lastL ? out : nullptr, N);
    }
}